// Round 13
// baseline (409.115 us; speedup 1.0000x reference)
//
#include <hip/hip_runtime.h>
#include <stdint.h>
#include <math.h>

// ReformerAttention on MI355X — fp32 I/O. B=2,T=2048,E=512,H=8,Dh=64,
// 2 hash rounds, buckets<32 attend.
// Projection row p = logical (b'=p>>11, t'=p&2047); gathers input row (b=p&1, t=p>>1).
//
// 7 launches:
//   front(qkv Q,K + weight-split + zero attn/cnt)  [z=0,1 qkv; z=2 prep]
//   mfma(V, gather)  -> hash(+hist) -> scan(+tasks) -> scatter2
//   -> attn_task -> mfma(out, perm)
// Q,K proj: fp32 64x64 tile (r9 measured-best body; argmax needs exact fp32).
// V/out proj: bf16 MFMA 16x16x32, 3-term hi/lo split, 2x8 tiles/wave.

#define T_ 2048
#define E_ 512
#define H_ 8
#define DH_ 64
#define B_ 2
#define M_ 4096
#define NROUND 2
#define NBUCKET 32
#define NSEG 32
#define MAXTASK 5120

typedef short v8s __attribute__((ext_vector_type(8)));
typedef float v4f __attribute__((ext_vector_type(4)));

__device__ __forceinline__ float bf2f(uint16_t u) {
  union { uint32_t i; float f; } v; v.i = ((uint32_t)u) << 16; return v.f;
}
__device__ __forceinline__ uint16_t f2bf(float f) {
  union { float fv; uint32_t i; } v; v.fv = f;
  uint32_t x = v.i;
  x += 0x7fffu + ((x >> 16) & 1u);   // RN-even
  return (uint16_t)(x >> 16);
}
__device__ __forceinline__ void split8(const float4 a, const float4 b,
                                       v8s& h, v8s& l) {
  const float x[8] = {a.x, a.y, a.z, a.w, b.x, b.y, b.z, b.w};
#pragma unroll
  for (int j = 0; j < 8; j++) {
    const uint16_t hh = f2bf(x[j]);
    h[j] = (short)hh;
    l[j] = (short)f2bf(x[j] - bf2f(hh));
  }
}

// ---------------------------------------------------------------------------
// front: z=0 -> Q proj, z=1 -> K proj (r9 64x64 fp32 body, bit-identical),
//        z=2 -> prep slice (Wv/Wo hi-lo split, zero attn, zero cnt/ntasks).
// grid (8, 64, 3), 256 threads.
// ---------------------------------------------------------------------------
__global__ __launch_bounds__(256) void front_kernel(
    const float* __restrict__ Xq, const float* __restrict__ Xk,
    const float* __restrict__ Wq, const float* __restrict__ bq,
    const float* __restrict__ Wk, const float* __restrict__ bk,
    float* __restrict__ Qo, float* __restrict__ Ko,
    const float* __restrict__ Wv, const float* __restrict__ Wo,
    uint16_t* __restrict__ Wvh, uint16_t* __restrict__ Wvl,
    uint16_t* __restrict__ Woh, uint16_t* __restrict__ Wol,
    float* __restrict__ attn, int* __restrict__ cnt)
{
  __shared__ __align__(16) float As[16 * 68];
  __shared__ __align__(16) float Bs[16 * 68];

  if (blockIdx.z == 2) {                 // prep slice: 512 blocks x 256 thr
    const int f = blockIdx.y * gridDim.x + blockIdx.x;   // 0..511
    const int g = f * 256 + threadIdx.x;                 // 0..131071
    const int n = E_ * E_;
#pragma unroll
    for (int it = 0; it < 4; it++) {     // 2*E*E = 524288 weight elems
      const int i = g + it * 131072;
      const float* s; uint16_t* h; uint16_t* l; int j = i;
      if (i < n) { s = Wv; h = Wvh; l = Wvl; }
      else       { s = Wo; h = Woh; l = Wol; j = i - n; }
      const float x = s[j];
      const uint16_t hh = f2bf(x);
      h[j] = hh;
      l[j] = f2bf(x - bf2f(hh));
    }
    float4* a4 = (float4*)attn;          // M_*E_/4 = 524288 float4
#pragma unroll
    for (int it = 0; it < 4; it++)
      a4[g + it * 131072] = make_float4(0.f, 0.f, 0.f, 0.f);
    if (g < 2 * NSEG * NBUCKET + 1) cnt[g] = 0;
    return;
  }

  const float* X; const float* W; const float* bias; float* C;
  if (blockIdx.z == 0) { X = Xq; W = Wq; bias = bq; C = Qo; }
  else                 { X = Xk; W = Wk; bias = bk; C = Ko; }

  const int tid = threadIdx.x;
  const int tx = tid & 15, ty = tid >> 4;
  const int m0 = blockIdx.y * 64, n0 = blockIdx.x * 64;
  const int lrow = tid >> 2;
  const int lk = (tid & 3) * 4;
  const int am = m0 + lrow;
  const long abase = ((long)(am & 1) * T_ + (am >> 1)) * E_ + lk;
  const long bbase = (long)(n0 + lrow) * E_ + lk;

  float acc[4][4] = {};

  for (int k0 = 0; k0 < E_; k0 += 16) {
    const float4 av4 = *(const float4*)(X + abase + k0);
    const float4 bv4 = *(const float4*)(W + bbase + k0);
    __syncthreads();
    As[(lk + 0) * 68 + lrow] = av4.x;
    As[(lk + 1) * 68 + lrow] = av4.y;
    As[(lk + 2) * 68 + lrow] = av4.z;
    As[(lk + 3) * 68 + lrow] = av4.w;
    Bs[(lk + 0) * 68 + lrow] = bv4.x;
    Bs[(lk + 1) * 68 + lrow] = bv4.y;
    Bs[(lk + 2) * 68 + lrow] = bv4.z;
    Bs[(lk + 3) * 68 + lrow] = bv4.w;
    __syncthreads();
#pragma unroll
    for (int kk = 0; kk < 16; kk++) {
      const float4 a = *(const float4*)&As[kk * 68 + ty * 4];
      const float4 b = *(const float4*)&Bs[kk * 68 + tx * 4];
      const float avr[4] = {a.x, a.y, a.z, a.w};
      const float bvr[4] = {b.x, b.y, b.z, b.w};
#pragma unroll
      for (int i = 0; i < 4; i++)
#pragma unroll
        for (int j = 0; j < 4; j++) acc[i][j] += avr[i] * bvr[j];
    }
  }

#pragma unroll
  for (int i = 0; i < 4; i++) {
    const int mm = m0 + ty * 4 + i;
    float4 o;
    o.x = acc[i][0] + bias[n0 + tx * 4 + 0];
    o.y = acc[i][1] + bias[n0 + tx * 4 + 1];
    o.z = acc[i][2] + bias[n0 + tx * 4 + 2];
    o.w = acc[i][3] + bias[n0 + tx * 4 + 3];
    *(float4*)(C + (long)mm * E_ + n0 + tx * 4) = o;
  }
}

// ---------------------------------------------------------------------------
// bf16 MFMA GEMM, A fp32 converted in-register, 2x8 tiles/wave (32x128).
// Split work amortized over 128 output cols (was 64). grid (M/128, E/128).
// ---------------------------------------------------------------------------
__global__ __launch_bounds__(256) void mfma_gemm(
    const float* __restrict__ A,
    const uint16_t* __restrict__ Bh, const uint16_t* __restrict__ Bl,
    const float* __restrict__ bias, float* __restrict__ C,
    int gatherA, int permC)
{
  const int wid = threadIdx.x >> 6, lane = threadIdx.x & 63;
  const int m0 = (blockIdx.x * 4 + wid) * 32;
  const int n0 = blockIdx.y * 128;
  const int l15 = lane & 15, quad = lane >> 4;

  const int ra0 = m0 + l15, ra1 = m0 + 16 + l15;
  const long sa0 = (gatherA ? ((long)(ra0 & 1) * T_ + (ra0 >> 1)) : (long)ra0) * E_ + quad * 8;
  const long sa1 = (gatherA ? ((long)(ra1 & 1) * T_ + (ra1 >> 1)) : (long)ra1) * E_ + quad * 8;
  long boff[8];
#pragma unroll
  for (int j = 0; j < 8; j++) boff[j] = (long)(n0 + j * 16 + l15) * E_ + quad * 8;

  v4f acc[2][8] = {};
  for (int k0 = 0; k0 < E_; k0 += 32) {
    v8s ah0, al0, ah1, al1;
    split8(*(const float4*)(A + sa0 + k0), *(const float4*)(A + sa0 + k0 + 4),
           ah0, al0);
    split8(*(const float4*)(A + sa1 + k0), *(const float4*)(A + sa1 + k0 + 4),
           ah1, al1);
#pragma unroll
    for (int j = 0; j < 8; j++) {
      const v8s bh = *(const v8s*)(Bh + boff[j] + k0);
      const v8s bl = *(const v8s*)(Bl + boff[j] + k0);
      acc[0][j] = __builtin_amdgcn_mfma_f32_16x16x32_bf16(ah0, bh, acc[0][j], 0, 0, 0);
      acc[1][j] = __builtin_amdgcn_mfma_f32_16x16x32_bf16(ah1, bh, acc[1][j], 0, 0, 0);
      acc[0][j] = __builtin_amdgcn_mfma_f32_16x16x32_bf16(ah0, bl, acc[0][j], 0, 0, 0);
      acc[1][j] = __builtin_amdgcn_mfma_f32_16x16x32_bf16(ah1, bl, acc[1][j], 0, 0, 0);
      acc[0][j] = __builtin_amdgcn_mfma_f32_16x16x32_bf16(al0, bh, acc[0][j], 0, 0, 0);
      acc[1][j] = __builtin_amdgcn_mfma_f32_16x16x32_bf16(al1, bh, acc[1][j], 0, 0, 0);
    }
  }

#pragma unroll
  for (int i = 0; i < 2; i++)
#pragma unroll
    for (int j = 0; j < 8; j++) {
      const int colg = n0 + j * 16 + l15;
      const float bb = bias[colg];
#pragma unroll
      for (int r = 0; r < 4; r++) {
        const int mm = m0 + i * 16 + quad * 4 + r;
        const int crow = permC ? ((mm & (T_ - 1)) * B_ + (mm >> 11)) : mm;
        C[(long)crow * E_ + colg] = acc[i][j][r] + bb;
      }
    }
}

// ---------------------------------------------------------------------------
// LSH hash: W[r] staged in LDS, 2-j unroll, 4-way split partials, inline
// histogram (cnt pre-zeroed by front). First-index argmax preserved.
// ---------------------------------------------------------------------------
__global__ __launch_bounds__(128) void hash_kernel(
    const float* __restrict__ Q, const float* __restrict__ K,
    const float* __restrict__ lshW, const float* __restrict__ lshb,
    int* __restrict__ qh, int* __restrict__ kh,
    int* __restrict__ qcnt, int* __restrict__ kcnt)
{
  __shared__ __align__(16) float xs[128 * 68];
  __shared__ __align__(16) float ws[64 * 64];
  const int tid = threadIdx.x;
  const int tau0 = blockIdx.x * 128;
  const int src = tau0 >> 16;
  const int r = (tau0 >> 15) & 1;
  const int rowbase = tau0 & 32767;
  const float* X = src ? K : Q;
  int* outh = src ? kh : qh;
  int* cnt = src ? kcnt : qcnt;

  const float4* g = (const float4*)(X + (long)rowbase * 64);
#pragma unroll
  for (int it = 0; it < 16; it++) {
    const int gidx = it * 128 + tid;
    const int row = gidx >> 4, c4 = gidx & 15;
    *(float4*)&xs[row * 68 + c4 * 4] = g[gidx];
  }
  const float4* wg = (const float4*)(lshW + (long)r * DH_ * DH_);
#pragma unroll
  for (int it = 0; it < 8; it++) {
    const int fidx = it * 128 + tid;
    ((float4*)ws)[fidx] = wg[fidx];
  }
  __syncthreads();

  float4 x[16];
#pragma unroll
  for (int i = 0; i < 16; i++) x[i] = *(const float4*)&xs[tid * 68 + i * 4];

  const float* bb = lshb + r * DH_;

  float best = -INFINITY; int bi = 0;
  for (int j = 0; j < 64; j += 2) {
    const float4* w0 = (const float4*)&ws[j * 64];
    const float4* w1 = (const float4*)&ws[(j + 1) * 64];
    float p0 = 0.f, p1 = 0.f, p2 = 0.f, p3 = 0.f;
    float q0 = 0.f, q1 = 0.f, q2 = 0.f, q3 = 0.f;
#pragma unroll
    for (int d = 0; d < 16; d++) {
      const float4 a = w0[d];
      const float4 c = w1[d];
      p0 += x[d].x * a.x; p1 += x[d].y * a.y;
      p2 += x[d].z * a.z; p3 += x[d].w * a.w;
      q0 += x[d].x * c.x; q1 += x[d].y * c.y;
      q2 += x[d].z * c.z; q3 += x[d].w * c.w;
    }
    const float s0 = ((p0 + p1) + (p2 + p3)) + bb[j];
    const float s1 = ((q0 + q1) + (q2 + q3)) + bb[j + 1];
    if (s0 > best) { best = s0; bi = j; }
    if (s1 > best) { best = s1; bi = j + 1; }
  }

  const int rowidx = rowbase + tid;
  const int p = rowidx >> 3, h = rowidx & 7;
  const int b = p >> 11, t = p & (T_ - 1);
  const int seg = (r * 16) + b * H_ + h;
  outh[seg * T_ + t] = bi;
  if (bi < NBUCKET) atomicAdd(&cnt[seg * NBUCKET + bi], 1);
}

// ---------------------------------------------------------------------------
// Scan (+16-query task emission); fused k/q scatter. Unchanged.
// ---------------------------------------------------------------------------
__global__ void scan_kernel(const int* __restrict__ kcnt, int* __restrict__ koff,
                            int* __restrict__ kcur,
                            const int* __restrict__ qcnt, int* __restrict__ qoff,
                            int* __restrict__ qcur,
                            int* __restrict__ ntasks, int* __restrict__ tasks)
{
  const int t = threadIdx.x;
  const int seg = t & 31;
  const int* cnt = (t < 32) ? kcnt : qcnt;
  int* off = (t < 32) ? koff : qoff;
  int* cur = (t < 32) ? kcur : qcur;
  int run = 0;
  for (int b = 0; b < NBUCKET; b++) {
    off[seg * (NBUCKET + 1) + b] = run;
    cur[seg * NBUCKET + b] = run;
    run += cnt[seg * NBUCKET + b];
  }
  off[seg * (NBUCKET + 1) + NBUCKET] = run;

  if (t >= 32) {
    for (int b = 0; b < NBUCKET; b++) {
      const int nq = cnt[seg * NBUCKET + b];
      if (nq > 0) {
        const int nt = (nq + 15) >> 4;
        const int base = atomicAdd(ntasks, nt);
        for (int i = 0; i < nt; i++)
          tasks[base + i] = (seg << 16) | (b << 8) | i;
      }
    }
  }
}

__global__ __launch_bounds__(256) void scatter2_kernel(
    const int* __restrict__ kh, const int* __restrict__ qh,
    int* __restrict__ kcur, int* __restrict__ qcur,
    int* __restrict__ klist, int* __restrict__ qlist)
{
  const int idx = blockIdx.x * 256 + threadIdx.x;
  const int y = blockIdx.y;
  const int* hsh = y ? qh : kh;
  int* cur = y ? qcur : kcur;
  int* list = y ? qlist : klist;
  const int v = hsh[idx];
  if (v < NBUCKET) {
    const int seg = idx >> 11;
    const int pos = atomicAdd(&cur[seg * NBUCKET + v], 1);
    list[seg * T_ + pos] = idx & (T_ - 1);
  }
}

// ---------------------------------------------------------------------------
// Task-parallel dense bucket attention (unchanged — proven).
// ---------------------------------------------------------------------------
__global__ __launch_bounds__(256) void attn_task(
    const float* __restrict__ Q, const float* __restrict__ K,
    const float* __restrict__ V,
    const int* __restrict__ qlist, const int* __restrict__ qoff,
    const int* __restrict__ klist, const int* __restrict__ koff,
    const int* __restrict__ tasks, const int* __restrict__ ntasks,
    float* __restrict__ attn)
{
  __shared__ __align__(16) float QPs[16 * 68];
  __shared__ __align__(16) float Ks[64 * 68];
  __shared__ __align__(16) float Vs[64 * 68];

  if ((int)blockIdx.x >= *ntasks) return;
  const int tk = tasks[blockIdx.x];
  const int seg = tk >> 16, bucket = (tk >> 8) & 255, qt = tk & 255;
  const int ctx = seg & 15;
  const int b = ctx >> 3, h = ctx & 7;

  const int qlo = qoff[seg * (NBUCKET + 1) + bucket] + qt * 16;
  const int nqt = min(16, qoff[seg * (NBUCKET + 1) + bucket + 1] - qlo);
  const int klo = koff[seg * (NBUCKET + 1) + bucket];
  const int nk  = koff[seg * (NBUCKET + 1) + bucket + 1] - klo;
  if (nk == 0) return;

  const int tid = threadIdx.x;
  const int qrow = tid >> 4, col = tid & 15;
  const float* Qb = Q + ((long)b * T_) * E_ + h * DH_;
  const float* Kb = K + ((long)b * T_) * E_ + h * DH_;
  const float* Vb = V + ((long)b * T_) * E_ + h * DH_;
  const int* ql = qlist + seg * T_;
  const int* kl = klist + seg * T_;

  {
    float4 v = make_float4(0.f, 0.f, 0.f, 0.f);
    if (qrow < nqt) v = *(const float4*)(Qb + (long)ql[qlo + qrow] * E_ + col * 4);
    *(float4*)&QPs[qrow * 68 + col * 4] = v;
  }
  __syncthreads();
  float4 qreg[16];
#pragma unroll
  for (int i = 0; i < 16; i++) qreg[i] = *(const float4*)&QPs[qrow * 68 + i * 4];

  float l = 0.f;
  float4 o = make_float4(0.f, 0.f, 0.f, 0.f);

  for (int kt = 0; kt < nk; kt += 64) {
    const int nkt = min(64, nk - kt);
    __syncthreads();
#pragma unroll
    for (int it = 0; it < 4; it++) {
      const int fidx = it * 256 + tid;
      const int row = fidx >> 4, c4 = fidx & 15;
      if (row < nkt) {
        const long src = (long)kl[klo + kt + row] * E_ + c4 * 4;
        *(float4*)&Ks[row * 68 + c4 * 4] = *(const float4*)(Kb + src);
        *(float4*)&Vs[row * 68 + c4 * 4] = *(const float4*)(Vb + src);
      } else {
        *(float4*)&Vs[row * 68 + c4 * 4] = make_float4(0.f, 0.f, 0.f, 0.f);
      }
    }
    __syncthreads();
#pragma unroll
    for (int kk = 0; kk < 4; kk++) {
      const int k = kk * 16 + col;
      float p = 0.f;
      if (k < nkt) {
        const float* kp = &Ks[k * 68];
        float s = 0.f;
#pragma unroll
        for (int d4 = 0; d4 < 16; d4++) {
          const float4 c = *(const float4*)(kp + d4 * 4);
          s += qreg[d4].x * c.x + qreg[d4].y * c.y +
               qreg[d4].z * c.z + qreg[d4].w * c.w;
        }
        p = __expf(s * 0.125f);
      }
      QPs[qrow * 68 + k] = p;
    }
    __syncthreads();
    const int nk4 = (nkt + 3) >> 2;
#pragma unroll 2
    for (int k4 = 0; k4 < nk4; k4++) {
      const float4 pk = *(const float4*)&QPs[qrow * 68 + k4 * 4];
      const float4 v0 = *(const float4*)&Vs[(k4 * 4 + 0) * 68 + col * 4];
      const float4 v1 = *(const float4*)&Vs[(k4 * 4 + 1) * 68 + col * 4];
      const float4 v2 = *(const float4*)&Vs[(k4 * 4 + 2) * 68 + col * 4];
      const float4 v3 = *(const float4*)&Vs[(k4 * 4 + 3) * 68 + col * 4];
      l += (pk.x + pk.y) + (pk.z + pk.w);
      o.x += pk.x * v0.x + pk.y * v1.x + pk.z * v2.x + pk.w * v3.x;
      o.y += pk.x * v0.y + pk.y * v1.y + pk.z * v2.y + pk.w * v3.y;
      o.z += pk.x * v0.z + pk.y * v1.z + pk.z * v2.z + pk.w * v3.z;
      o.w += pk.x * v0.w + pk.y * v1.w + pk.z * v2.w + pk.w * v3.w;
    }
  }

  if (qrow < nqt) {
    const float inv = 0.5f / l;
    const int t = ql[qlo + qrow];
    float* op = attn + ((long)b * T_ + t) * E_ + h * DH_ + col * 4;
    atomicAdd(op + 0, o.x * inv);
    atomicAdd(op + 1, o.y * inv);
    atomicAdd(op + 2, o.z * inv);
    atomicAdd(op + 3, o.w * inv);
  }
}

// ---------------------------------------------------------------------------
extern "C" void kernel_launch(void* const* d_in, const int* in_sizes, int n_in,
                              void* d_out, int out_size, void* d_ws, size_t ws_size,
                              hipStream_t stream) {
  const float* query = (const float*)d_in[0];
  const float* key   = (const float*)d_in[1];
  const float* value = (const float*)d_in[2];
  const float* Wq = (const float*)d_in[3];
  const float* bq = (const float*)d_in[4];
  const float* Wk = (const float*)d_in[5];
  const float* bk = (const float*)d_in[6];
  const float* Wv = (const float*)d_in[7];
  const float* bv = (const float*)d_in[8];
  const float* Wo = (const float*)d_in[9];
  const float* bo = (const float*)d_in[10];
  const float* lshW = (const float*)d_in[11];
  const float* lshb = (const float*)d_in[12];

  const size_t MSZ = (size_t)M_ * E_;
  float* Q    = (float*)d_ws;
  float* K    = Q + MSZ;
  float* V    = K + MSZ;
  float* attn = V + MSZ;
  int* qh     = (int*)(attn + MSZ);
  int* kh     = qh + NSEG * T_;
  int* klist  = kh + NSEG * T_;
  int* qlist  = klist + NSEG * T_;
  int* kcnt   = qlist + NSEG * T_;       // start of zeroed region
  int* qcnt   = kcnt + NSEG * NBUCKET;
  int* ntasks = qcnt + NSEG * NBUCKET;   // end of zeroed region
  int* kcur   = ntasks + 1;
  int* qcur   = kcur + NSEG * NBUCKET;
  int* koff   = qcur + NSEG * NBUCKET;
  int* qoff   = koff + NSEG * (NBUCKET + 1);
  int* tasks  = qoff + NSEG * (NBUCKET + 1);
  uint16_t* Wvh = (uint16_t*)(((uintptr_t)(tasks + MAXTASK) + 15) & ~(uintptr_t)15);
  uint16_t* Wvl = Wvh + (size_t)E_ * E_;
  uint16_t* Woh = Wvl + (size_t)E_ * E_;
  uint16_t* Wol = Woh + (size_t)E_ * E_;

  front_kernel<<<dim3(E_ / 64, M_ / 64, 3), 256, 0, stream>>>(
      query, key, Wq, bq, Wk, bk, Q, K,
      Wv, Wo, Wvh, Wvl, Woh, Wol, attn, kcnt);
  mfma_gemm<<<dim3(M_ / 128, E_ / 128), 256, 0, stream>>>(
      value, Wvh, Wvl, bv, V, 1, 0);
  hash_kernel<<<dim3(1024), 128, 0, stream>>>(
      Q, K, lshW, lshb, qh, kh, qcnt, kcnt);
  scan_kernel<<<dim3(1), 64, 0, stream>>>(kcnt, koff, kcur, qcnt, qoff, qcur,
                                          ntasks, tasks);
  scatter2_kernel<<<dim3(NSEG * T_ / 256, 2), 256, 0, stream>>>(
      kh, qh, kcur, qcur, klist, qlist);
  attn_task<<<dim3(MAXTASK), 256, 0, stream>>>(
      Q, K, V, qlist, qoff, klist, koff, tasks, ntasks, attn);
  mfma_gemm<<<dim3(M_ / 128, E_ / 128), 256, 0, stream>>>(
      attn, Woh, Wol, bo, (float*)d_out, 0, 1);
}

// Round 14
// 363.205 us; speedup vs baseline: 1.1264x; 1.1264x over previous
//
#include <hip/hip_runtime.h>
#include <stdint.h>
#include <math.h>

// ReformerAttention on MI355X — fp32 I/O. B=2,T=2048,E=512,H=8,Dh=64,
// 2 hash rounds, buckets<32 attend.
// Projection row p = logical (b'=p>>11, t'=p&2047); gathers input row (b=p&1, t=p>>1).
//
// 7 launches:
//   front(qkv Q,K + weight-split + zero attn/cnt)  [z=0,1 qkv; z=2 prep]
//   mfma(V, gather)  -> hash(+hist) -> scan(+tasks) -> scatter2
//   -> attn_task -> mfma(out, perm)
// Q,K proj: fp32 64x64 tile (argmax needs exact fp32; measured plateau ~70us).
// V/out proj: bf16 MFMA 16x16x32, 3-term hi/lo split, 2x4 tiles/wave,
//   grid 256 blocks (1/CU) — 2x8/128-block variant regressed (r13).

#define T_ 2048
#define E_ 512
#define H_ 8
#define DH_ 64
#define B_ 2
#define M_ 4096
#define NROUND 2
#define NBUCKET 32
#define NSEG 32
#define MAXTASK 5120

typedef short v8s __attribute__((ext_vector_type(8)));
typedef float v4f __attribute__((ext_vector_type(4)));

__device__ __forceinline__ float bf2f(uint16_t u) {
  union { uint32_t i; float f; } v; v.i = ((uint32_t)u) << 16; return v.f;
}
__device__ __forceinline__ uint16_t f2bf(float f) {
  union { float fv; uint32_t i; } v; v.fv = f;
  uint32_t x = v.i;
  x += 0x7fffu + ((x >> 16) & 1u);   // RN-even
  return (uint16_t)(x >> 16);
}
__device__ __forceinline__ void split8(const float4 a, const float4 b,
                                       v8s& h, v8s& l) {
  const float x[8] = {a.x, a.y, a.z, a.w, b.x, b.y, b.z, b.w};
#pragma unroll
  for (int j = 0; j < 8; j++) {
    const uint16_t hh = f2bf(x[j]);
    h[j] = (short)hh;
    l[j] = (short)f2bf(x[j] - bf2f(hh));
  }
}

// ---------------------------------------------------------------------------
// front: z=0 -> Q proj, z=1 -> K proj (64x64 fp32 body, bit-identical),
//        z=2 -> prep slice (Wv/Wo hi-lo split, zero attn, zero cnt/ntasks).
// grid (8, 64, 3), 256 threads.
// ---------------------------------------------------------------------------
__global__ __launch_bounds__(256) void front_kernel(
    const float* __restrict__ Xq, const float* __restrict__ Xk,
    const float* __restrict__ Wq, const float* __restrict__ bq,
    const float* __restrict__ Wk, const float* __restrict__ bk,
    float* __restrict__ Qo, float* __restrict__ Ko,
    const float* __restrict__ Wv, const float* __restrict__ Wo,
    uint16_t* __restrict__ Wvh, uint16_t* __restrict__ Wvl,
    uint16_t* __restrict__ Woh, uint16_t* __restrict__ Wol,
    float* __restrict__ attn, int* __restrict__ cnt)
{
  __shared__ __align__(16) float As[16 * 68];
  __shared__ __align__(16) float Bs[16 * 68];

  if (blockIdx.z == 2) {                 // prep slice: 512 blocks x 256 thr
    const int f = blockIdx.y * gridDim.x + blockIdx.x;   // 0..511
    const int g = f * 256 + threadIdx.x;                 // 0..131071
    const int n = E_ * E_;
#pragma unroll
    for (int it = 0; it < 4; it++) {     // 2*E*E = 524288 weight elems
      const int i = g + it * 131072;
      const float* s; uint16_t* h; uint16_t* l; int j = i;
      if (i < n) { s = Wv; h = Wvh; l = Wvl; }
      else       { s = Wo; h = Woh; l = Wol; j = i - n; }
      const float x = s[j];
      const uint16_t hh = f2bf(x);
      h[j] = hh;
      l[j] = f2bf(x - bf2f(hh));
    }
    float4* a4 = (float4*)attn;          // M_*E_/4 = 524288 float4
#pragma unroll
    for (int it = 0; it < 4; it++)
      a4[g + it * 131072] = make_float4(0.f, 0.f, 0.f, 0.f);
    if (g < 2 * NSEG * NBUCKET + 1) cnt[g] = 0;
    return;
  }

  const float* X; const float* W; const float* bias; float* C;
  if (blockIdx.z == 0) { X = Xq; W = Wq; bias = bq; C = Qo; }
  else                 { X = Xk; W = Wk; bias = bk; C = Ko; }

  const int tid = threadIdx.x;
  const int tx = tid & 15, ty = tid >> 4;
  const int m0 = blockIdx.y * 64, n0 = blockIdx.x * 64;
  const int lrow = tid >> 2;
  const int lk = (tid & 3) * 4;
  const int am = m0 + lrow;
  const long abase = ((long)(am & 1) * T_ + (am >> 1)) * E_ + lk;
  const long bbase = (long)(n0 + lrow) * E_ + lk;

  float acc[4][4] = {};

  for (int k0 = 0; k0 < E_; k0 += 16) {
    const float4 av4 = *(const float4*)(X + abase + k0);
    const float4 bv4 = *(const float4*)(W + bbase + k0);
    __syncthreads();
    As[(lk + 0) * 68 + lrow] = av4.x;
    As[(lk + 1) * 68 + lrow] = av4.y;
    As[(lk + 2) * 68 + lrow] = av4.z;
    As[(lk + 3) * 68 + lrow] = av4.w;
    Bs[(lk + 0) * 68 + lrow] = bv4.x;
    Bs[(lk + 1) * 68 + lrow] = bv4.y;
    Bs[(lk + 2) * 68 + lrow] = bv4.z;
    Bs[(lk + 3) * 68 + lrow] = bv4.w;
    __syncthreads();
#pragma unroll
    for (int kk = 0; kk < 16; kk++) {
      const float4 a = *(const float4*)&As[kk * 68 + ty * 4];
      const float4 b = *(const float4*)&Bs[kk * 68 + tx * 4];
      const float avr[4] = {a.x, a.y, a.z, a.w};
      const float bvr[4] = {b.x, b.y, b.z, b.w};
#pragma unroll
      for (int i = 0; i < 4; i++)
#pragma unroll
        for (int j = 0; j < 4; j++) acc[i][j] += avr[i] * bvr[j];
    }
  }

#pragma unroll
  for (int i = 0; i < 4; i++) {
    const int mm = m0 + ty * 4 + i;
    float4 o;
    o.x = acc[i][0] + bias[n0 + tx * 4 + 0];
    o.y = acc[i][1] + bias[n0 + tx * 4 + 1];
    o.z = acc[i][2] + bias[n0 + tx * 4 + 2];
    o.w = acc[i][3] + bias[n0 + tx * 4 + 3];
    *(float4*)(C + (long)mm * E_ + n0 + tx * 4) = o;
  }
}

// ---------------------------------------------------------------------------
// bf16 MFMA GEMM, A fp32 converted in-register, 2x4 tiles/wave (32x64).
// grid (M/128, E/64) = 256 blocks (1/CU). r11 measured-best body.
// ---------------------------------------------------------------------------
__global__ __launch_bounds__(256) void mfma_gemm(
    const float* __restrict__ A,
    const uint16_t* __restrict__ Bh, const uint16_t* __restrict__ Bl,
    const float* __restrict__ bias, float* __restrict__ C,
    int gatherA, int permC)
{
  const int wid = threadIdx.x >> 6, lane = threadIdx.x & 63;
  const int m0 = (blockIdx.x * 4 + wid) * 32;
  const int n0 = blockIdx.y * 64;
  const int l15 = lane & 15, quad = lane >> 4;

  const int ra0 = m0 + l15, ra1 = m0 + 16 + l15;
  const long sa0 = (gatherA ? ((long)(ra0 & 1) * T_ + (ra0 >> 1)) : (long)ra0) * E_ + quad * 8;
  const long sa1 = (gatherA ? ((long)(ra1 & 1) * T_ + (ra1 >> 1)) : (long)ra1) * E_ + quad * 8;
  long boff[4];
#pragma unroll
  for (int j = 0; j < 4; j++) boff[j] = (long)(n0 + j * 16 + l15) * E_ + quad * 8;

  v4f acc[2][4] = {};
  for (int k0 = 0; k0 < E_; k0 += 32) {
    v8s ah0, al0, ah1, al1;
    split8(*(const float4*)(A + sa0 + k0), *(const float4*)(A + sa0 + k0 + 4),
           ah0, al0);
    split8(*(const float4*)(A + sa1 + k0), *(const float4*)(A + sa1 + k0 + 4),
           ah1, al1);
    v8s bh[4], bl[4];
#pragma unroll
    for (int j = 0; j < 4; j++) {
      bh[j] = *(const v8s*)(Bh + boff[j] + k0);
      bl[j] = *(const v8s*)(Bl + boff[j] + k0);
    }
#pragma unroll
    for (int j = 0; j < 4; j++) {
      acc[0][j] = __builtin_amdgcn_mfma_f32_16x16x32_bf16(ah0, bh[j], acc[0][j], 0, 0, 0);
      acc[1][j] = __builtin_amdgcn_mfma_f32_16x16x32_bf16(ah1, bh[j], acc[1][j], 0, 0, 0);
    }
#pragma unroll
    for (int j = 0; j < 4; j++) {
      acc[0][j] = __builtin_amdgcn_mfma_f32_16x16x32_bf16(ah0, bl[j], acc[0][j], 0, 0, 0);
      acc[1][j] = __builtin_amdgcn_mfma_f32_16x16x32_bf16(ah1, bl[j], acc[1][j], 0, 0, 0);
    }
#pragma unroll
    for (int j = 0; j < 4; j++) {
      acc[0][j] = __builtin_amdgcn_mfma_f32_16x16x32_bf16(al0, bh[j], acc[0][j], 0, 0, 0);
      acc[1][j] = __builtin_amdgcn_mfma_f32_16x16x32_bf16(al1, bh[j], acc[1][j], 0, 0, 0);
    }
  }

#pragma unroll
  for (int i = 0; i < 2; i++)
#pragma unroll
    for (int j = 0; j < 4; j++) {
      const int colg = n0 + j * 16 + l15;
      const float bb = bias[colg];
#pragma unroll
      for (int r = 0; r < 4; r++) {
        const int mm = m0 + i * 16 + quad * 4 + r;
        const int crow = permC ? ((mm & (T_ - 1)) * B_ + (mm >> 11)) : mm;
        C[(long)crow * E_ + colg] = acc[i][j][r] + bb;
      }
    }
}

// ---------------------------------------------------------------------------
// LSH hash: W[r] staged in LDS, 2-j unroll, 4-way split partials, inline
// histogram (cnt pre-zeroed by front). First-index argmax preserved.
// ---------------------------------------------------------------------------
__global__ __launch_bounds__(128) void hash_kernel(
    const float* __restrict__ Q, const float* __restrict__ K,
    const float* __restrict__ lshW, const float* __restrict__ lshb,
    int* __restrict__ qh, int* __restrict__ kh,
    int* __restrict__ qcnt, int* __restrict__ kcnt)
{
  __shared__ __align__(16) float xs[128 * 68];
  __shared__ __align__(16) float ws[64 * 64];
  const int tid = threadIdx.x;
  const int tau0 = blockIdx.x * 128;
  const int src = tau0 >> 16;
  const int r = (tau0 >> 15) & 1;
  const int rowbase = tau0 & 32767;
  const float* X = src ? K : Q;
  int* outh = src ? kh : qh;
  int* cnt = src ? kcnt : qcnt;

  const float4* g = (const float4*)(X + (long)rowbase * 64);
#pragma unroll
  for (int it = 0; it < 16; it++) {
    const int gidx = it * 128 + tid;
    const int row = gidx >> 4, c4 = gidx & 15;
    *(float4*)&xs[row * 68 + c4 * 4] = g[gidx];
  }
  const float4* wg = (const float4*)(lshW + (long)r * DH_ * DH_);
#pragma unroll
  for (int it = 0; it < 8; it++) {
    const int fidx = it * 128 + tid;
    ((float4*)ws)[fidx] = wg[fidx];
  }
  __syncthreads();

  float4 x[16];
#pragma unroll
  for (int i = 0; i < 16; i++) x[i] = *(const float4*)&xs[tid * 68 + i * 4];

  const float* bb = lshb + r * DH_;

  float best = -INFINITY; int bi = 0;
  for (int j = 0; j < 64; j += 2) {
    const float4* w0 = (const float4*)&ws[j * 64];
    const float4* w1 = (const float4*)&ws[(j + 1) * 64];
    float p0 = 0.f, p1 = 0.f, p2 = 0.f, p3 = 0.f;
    float q0 = 0.f, q1 = 0.f, q2 = 0.f, q3 = 0.f;
#pragma unroll
    for (int d = 0; d < 16; d++) {
      const float4 a = w0[d];
      const float4 c = w1[d];
      p0 += x[d].x * a.x; p1 += x[d].y * a.y;
      p2 += x[d].z * a.z; p3 += x[d].w * a.w;
      q0 += x[d].x * c.x; q1 += x[d].y * c.y;
      q2 += x[d].z * c.z; q3 += x[d].w * c.w;
    }
    const float s0 = ((p0 + p1) + (p2 + p3)) + bb[j];
    const float s1 = ((q0 + q1) + (q2 + q3)) + bb[j + 1];
    if (s0 > best) { best = s0; bi = j; }
    if (s1 > best) { best = s1; bi = j + 1; }
  }

  const int rowidx = rowbase + tid;
  const int p = rowidx >> 3, h = rowidx & 7;
  const int b = p >> 11, t = p & (T_ - 1);
  const int seg = (r * 16) + b * H_ + h;
  outh[seg * T_ + t] = bi;
  if (bi < NBUCKET) atomicAdd(&cnt[seg * NBUCKET + bi], 1);
}

// ---------------------------------------------------------------------------
// Scan (+16-query task emission); fused k/q scatter. Unchanged.
// ---------------------------------------------------------------------------
__global__ void scan_kernel(const int* __restrict__ kcnt, int* __restrict__ koff,
                            int* __restrict__ kcur,
                            const int* __restrict__ qcnt, int* __restrict__ qoff,
                            int* __restrict__ qcur,
                            int* __restrict__ ntasks, int* __restrict__ tasks)
{
  const int t = threadIdx.x;
  const int seg = t & 31;
  const int* cnt = (t < 32) ? kcnt : qcnt;
  int* off = (t < 32) ? koff : qoff;
  int* cur = (t < 32) ? kcur : qcur;
  int run = 0;
  for (int b = 0; b < NBUCKET; b++) {
    off[seg * (NBUCKET + 1) + b] = run;
    cur[seg * NBUCKET + b] = run;
    run += cnt[seg * NBUCKET + b];
  }
  off[seg * (NBUCKET + 1) + NBUCKET] = run;

  if (t >= 32) {
    for (int b = 0; b < NBUCKET; b++) {
      const int nq = cnt[seg * NBUCKET + b];
      if (nq > 0) {
        const int nt = (nq + 15) >> 4;
        const int base = atomicAdd(ntasks, nt);
        for (int i = 0; i < nt; i++)
          tasks[base + i] = (seg << 16) | (b << 8) | i;
      }
    }
  }
}

__global__ __launch_bounds__(256) void scatter2_kernel(
    const int* __restrict__ kh, const int* __restrict__ qh,
    int* __restrict__ kcur, int* __restrict__ qcur,
    int* __restrict__ klist, int* __restrict__ qlist)
{
  const int idx = blockIdx.x * 256 + threadIdx.x;
  const int y = blockIdx.y;
  const int* hsh = y ? qh : kh;
  int* cur = y ? qcur : kcur;
  int* list = y ? qlist : klist;
  const int v = hsh[idx];
  if (v < NBUCKET) {
    const int seg = idx >> 11;
    const int pos = atomicAdd(&cur[seg * NBUCKET + v], 1);
    list[seg * T_ + pos] = idx & (T_ - 1);
  }
}

// ---------------------------------------------------------------------------
// Task-parallel dense bucket attention (unchanged — proven).
// ---------------------------------------------------------------------------
__global__ __launch_bounds__(256) void attn_task(
    const float* __restrict__ Q, const float* __restrict__ K,
    const float* __restrict__ V,
    const int* __restrict__ qlist, const int* __restrict__ qoff,
    const int* __restrict__ klist, const int* __restrict__ koff,
    const int* __restrict__ tasks, const int* __restrict__ ntasks,
    float* __restrict__ attn)
{
  __shared__ __align__(16) float QPs[16 * 68];
  __shared__ __align__(16) float Ks[64 * 68];
  __shared__ __align__(16) float Vs[64 * 68];

  if ((int)blockIdx.x >= *ntasks) return;
  const int tk = tasks[blockIdx.x];
  const int seg = tk >> 16, bucket = (tk >> 8) & 255, qt = tk & 255;
  const int ctx = seg & 15;
  const int b = ctx >> 3, h = ctx & 7;

  const int qlo = qoff[seg * (NBUCKET + 1) + bucket] + qt * 16;
  const int nqt = min(16, qoff[seg * (NBUCKET + 1) + bucket + 1] - qlo);
  const int klo = koff[seg * (NBUCKET + 1) + bucket];
  const int nk  = koff[seg * (NBUCKET + 1) + bucket + 1] - klo;
  if (nk == 0) return;

  const int tid = threadIdx.x;
  const int qrow = tid >> 4, col = tid & 15;
  const float* Qb = Q + ((long)b * T_) * E_ + h * DH_;
  const float* Kb = K + ((long)b * T_) * E_ + h * DH_;
  const float* Vb = V + ((long)b * T_) * E_ + h * DH_;
  const int* ql = qlist + seg * T_;
  const int* kl = klist + seg * T_;

  {
    float4 v = make_float4(0.f, 0.f, 0.f, 0.f);
    if (qrow < nqt) v = *(const float4*)(Qb + (long)ql[qlo + qrow] * E_ + col * 4);
    *(float4*)&QPs[qrow * 68 + col * 4] = v;
  }
  __syncthreads();
  float4 qreg[16];
#pragma unroll
  for (int i = 0; i < 16; i++) qreg[i] = *(const float4*)&QPs[qrow * 68 + i * 4];

  float l = 0.f;
  float4 o = make_float4(0.f, 0.f, 0.f, 0.f);

  for (int kt = 0; kt < nk; kt += 64) {
    const int nkt = min(64, nk - kt);
    __syncthreads();
#pragma unroll
    for (int it = 0; it < 4; it++) {
      const int fidx = it * 256 + tid;
      const int row = fidx >> 4, c4 = fidx & 15;
      if (row < nkt) {
        const long src = (long)kl[klo + kt + row] * E_ + c4 * 4;
        *(float4*)&Ks[row * 68 + c4 * 4] = *(const float4*)(Kb + src);
        *(float4*)&Vs[row * 68 + c4 * 4] = *(const float4*)(Vb + src);
      } else {
        *(float4*)&Vs[row * 68 + c4 * 4] = make_float4(0.f, 0.f, 0.f, 0.f);
      }
    }
    __syncthreads();
#pragma unroll
    for (int kk = 0; kk < 4; kk++) {
      const int k = kk * 16 + col;
      float p = 0.f;
      if (k < nkt) {
        const float* kp = &Ks[k * 68];
        float s = 0.f;
#pragma unroll
        for (int d4 = 0; d4 < 16; d4++) {
          const float4 c = *(const float4*)(kp + d4 * 4);
          s += qreg[d4].x * c.x + qreg[d4].y * c.y +
               qreg[d4].z * c.z + qreg[d4].w * c.w;
        }
        p = __expf(s * 0.125f);
      }
      QPs[qrow * 68 + k] = p;
    }
    __syncthreads();
    const int nk4 = (nkt + 3) >> 2;
#pragma unroll 2
    for (int k4 = 0; k4 < nk4; k4++) {
      const float4 pk = *(const float4*)&QPs[qrow * 68 + k4 * 4];
      const float4 v0 = *(const float4*)&Vs[(k4 * 4 + 0) * 68 + col * 4];
      const float4 v1 = *(const float4*)&Vs[(k4 * 4 + 1) * 68 + col * 4];
      const float4 v2 = *(const float4*)&Vs[(k4 * 4 + 2) * 68 + col * 4];
      const float4 v3 = *(const float4*)&Vs[(k4 * 4 + 3) * 68 + col * 4];
      l += (pk.x + pk.y) + (pk.z + pk.w);
      o.x += pk.x * v0.x + pk.y * v1.x + pk.z * v2.x + pk.w * v3.x;
      o.y += pk.x * v0.y + pk.y * v1.y + pk.z * v2.y + pk.w * v3.y;
      o.z += pk.x * v0.z + pk.y * v1.z + pk.z * v2.z + pk.w * v3.z;
      o.w += pk.x * v0.w + pk.y * v1.w + pk.z * v2.w + pk.w * v3.w;
    }
  }

  if (qrow < nqt) {
    const float inv = 0.5f / l;
    const int t = ql[qlo + qrow];
    float* op = attn + ((long)b * T_ + t) * E_ + h * DH_ + col * 4;
    atomicAdd(op + 0, o.x * inv);
    atomicAdd(op + 1, o.y * inv);
    atomicAdd(op + 2, o.z * inv);
    atomicAdd(op + 3, o.w * inv);
  }
}

// ---------------------------------------------------------------------------
extern "C" void kernel_launch(void* const* d_in, const int* in_sizes, int n_in,
                              void* d_out, int out_size, void* d_ws, size_t ws_size,
                              hipStream_t stream) {
  const float* query = (const float*)d_in[0];
  const float* key   = (const float*)d_in[1];
  const float* value = (const float*)d_in[2];
  const float* Wq = (const float*)d_in[3];
  const float* bq = (const float*)d_in[4];
  const float* Wk = (const float*)d_in[5];
  const float* bk = (const float*)d_in[6];
  const float* Wv = (const float*)d_in[7];
  const float* bv = (const float*)d_in[8];
  const float* Wo = (const float*)d_in[9];
  const float* bo = (const float*)d_in[10];
  const float* lshW = (const float*)d_in[11];
  const float* lshb = (const float*)d_in[12];

  const size_t MSZ = (size_t)M_ * E_;
  float* Q    = (float*)d_ws;
  float* K    = Q + MSZ;
  float* V    = K + MSZ;
  float* attn = V + MSZ;
  int* qh     = (int*)(attn + MSZ);
  int* kh     = qh + NSEG * T_;
  int* klist  = kh + NSEG * T_;
  int* qlist  = klist + NSEG * T_;
  int* kcnt   = qlist + NSEG * T_;       // start of zeroed region
  int* qcnt   = kcnt + NSEG * NBUCKET;
  int* ntasks = qcnt + NSEG * NBUCKET;   // end of zeroed region
  int* kcur   = ntasks + 1;
  int* qcur   = kcur + NSEG * NBUCKET;
  int* koff   = qcur + NSEG * NBUCKET;
  int* qoff   = koff + NSEG * (NBUCKET + 1);
  int* tasks  = qoff + NSEG * (NBUCKET + 1);
  uint16_t* Wvh = (uint16_t*)(((uintptr_t)(tasks + MAXTASK) + 15) & ~(uintptr_t)15);
  uint16_t* Wvl = Wvh + (size_t)E_ * E_;
  uint16_t* Woh = Wvl + (size_t)E_ * E_;
  uint16_t* Wol = Woh + (size_t)E_ * E_;

  front_kernel<<<dim3(E_ / 64, M_ / 64, 3), 256, 0, stream>>>(
      query, key, Wq, bq, Wk, bk, Q, K,
      Wv, Wo, Wvh, Wvl, Woh, Wol, attn, kcnt);
  mfma_gemm<<<dim3(M_ / 128, E_ / 64), 256, 0, stream>>>(
      value, Wvh, Wvl, bv, V, 1, 0);
  hash_kernel<<<dim3(1024), 128, 0, stream>>>(
      Q, K, lshW, lshb, qh, kh, qcnt, kcnt);
  scan_kernel<<<dim3(1), 64, 0, stream>>>(kcnt, koff, kcur, qcnt, qoff, qcur,
                                          ntasks, tasks);
  scatter2_kernel<<<dim3(NSEG * T_ / 256, 2), 256, 0, stream>>>(
      kh, qh, kcur, qcur, klist, qlist);
  attn_task<<<dim3(MAXTASK), 256, 0, stream>>>(
      Q, K, V, qlist, qoff, klist, koff, tasks, ntasks, attn);
  mfma_gemm<<<dim3(M_ / 128, E_ / 64), 256, 0, stream>>>(
      attn, Woh, Wol, bo, (float*)d_out, 0, 1);
}